// Round 1
// baseline (280.638 us; speedup 1.0000x reference)
//
#include <hip/hip_runtime.h>
#include <math.h>

typedef short short8 __attribute__((ext_vector_type(8)));
typedef float floatx4 __attribute__((ext_vector_type(4)));

#define N_ROWS 8192
#define KDIM 1024

// fp32 -> bf16 round-to-nearest-even
__device__ __forceinline__ unsigned short f2bf(float f) {
  unsigned int u = __float_as_uint(f);
  u += 0x7fffu + ((u >> 16) & 1u);
  return (unsigned short)(u >> 16);
}

// order-preserving float->int encoding for atomicMax
__device__ __forceinline__ int fenc(float f) {
  int i = __float_as_int(f);
  return i >= 0 ? i : (i ^ 0x7fffffff);
}
__device__ __forceinline__ float fdec(int e) {
  int b = e >= 0 ? e : (e ^ 0x7fffffff);
  return __int_as_float(b);
}

// One block per row: compute 1/||x||, write normalized bf16 row, init max slot.
__global__ __launch_bounds__(256) void normalize_kernel(
    const float* __restrict__ x, unsigned short* __restrict__ out,
    int* __restrict__ maxinit) {
  const int row = blockIdx.x;
  const int tid = threadIdx.x;
  const float4* xr = (const float4*)(x + (size_t)row * KDIM);
  float4 v = xr[tid];  // 256 threads * 4 = 1024 elements
  float ss = v.x * v.x + v.y * v.y + v.z * v.z + v.w * v.w;
#pragma unroll
  for (int off = 32; off > 0; off >>= 1) ss += __shfl_down(ss, off, 64);
  __shared__ float sred[4];
  if ((tid & 63) == 0) sred[tid >> 6] = ss;
  __syncthreads();
  const float total = sred[0] + sred[1] + sred[2] + sred[3];
  const float rnorm = rsqrtf(fmaxf(total, 1e-24f));
  ushort4 o;
  o.x = f2bf(v.x * rnorm);
  o.y = f2bf(v.y * rnorm);
  o.z = f2bf(v.z * rnorm);
  o.w = f2bf(v.w * rnorm);
  ((ushort4*)(out + (size_t)row * KDIM))[tid] = o;
  if (tid == 0) maxinit[row] = (int)0x80000000;  // encoded -inf floor
}

// 128x128 tile GEMM (A @ B^T, both row-major K-contiguous bf16) fused with
// row-max / col-max reduction into global encoded-int atomics.
__global__ __launch_bounds__(256) void gemm_max_kernel(
    const unsigned short* __restrict__ A, const unsigned short* __restrict__ B,
    int* __restrict__ rowmax, int* __restrict__ colmax) {
  constexpr int TM = 128, BK = 32, K = KDIM;
  __shared__ unsigned short sA[TM * BK];  // 8 KB, row-major 128 x 32
  __shared__ unsigned short sB[TM * BK];  // 8 KB

  const int bm = blockIdx.x, bn = blockIdx.y;
  const int tid = threadIdx.x;
  const int lane = tid & 63, wave = tid >> 6;
  const int wm = wave >> 1, wn = wave & 1;  // 2x2 waves of 64x64
  const int quad = lane >> 4, l16 = lane & 15;

  const char* Ab = (const char*)(A + (size_t)bm * TM * K);
  const char* Bb = (const char*)(B + (size_t)bn * TM * K);

  floatx4 acc[4][4] = {};

  const int o_l0 = wave * 2048;  // this wave's byte window within the 8KB tile
  for (int k0 = 0; k0 < K; k0 += BK) {
#pragma unroll
    for (int j = 0; j < 2; ++j) {
      const int obase = o_l0 + j * 1024;       // wave-uniform LDS byte base
      const int o = obase + lane * 16;         // this lane's tile byte offset
      const int r = o >> 6;                    // tile row (64 B per row)
      const int kb = o & 63;                   // byte offset within row
      const char* ga = Ab + (size_t)r * (K * 2) + (size_t)k0 * 2 + kb;
      const char* gb = Bb + (size_t)r * (K * 2) + (size_t)k0 * 2 + kb;
      __builtin_amdgcn_global_load_lds(
          (__attribute__((address_space(1))) void*)ga,
          (__attribute__((address_space(3))) void*)(((char*)sA) + obase), 16, 0, 0);
      __builtin_amdgcn_global_load_lds(
          (__attribute__((address_space(1))) void*)gb,
          (__attribute__((address_space(3))) void*)(((char*)sB) + obase), 16, 0, 0);
    }
    __syncthreads();

    short8 aF[4], bF[4];
#pragma unroll
    for (int mi = 0; mi < 4; ++mi)
      aF[mi] = *(const short8*)&sA[(wm * 64 + mi * 16 + l16) * BK + quad * 8];
#pragma unroll
    for (int ni = 0; ni < 4; ++ni)
      bF[ni] = *(const short8*)&sB[(wn * 64 + ni * 16 + l16) * BK + quad * 8];

#pragma unroll
    for (int mi = 0; mi < 4; ++mi)
#pragma unroll
      for (int ni = 0; ni < 4; ++ni)
        acc[mi][ni] = __builtin_amdgcn_mfma_f32_16x16x32_bf16(
            aF[mi], bF[ni], acc[mi][ni], 0, 0, 0);
    __syncthreads();
  }

  // C/D layout (verified m89): col = lane&15, row = quad*4 + reg.
  // Row maxes: max over 4 ni in-lane, then across the 16 lanes of a quad-group.
#pragma unroll
  for (int mi = 0; mi < 4; ++mi) {
#pragma unroll
    for (int r = 0; r < 4; ++r) {
      float v = fmaxf(fmaxf(acc[mi][0][r], acc[mi][1][r]),
                      fmaxf(acc[mi][2][r], acc[mi][3][r]));
#pragma unroll
      for (int m = 1; m < 16; m <<= 1) v = fmaxf(v, __shfl_xor(v, m, 64));
      if (l16 == 0) {
        const int grow = bm * TM + wm * 64 + mi * 16 + quad * 4 + r;
        atomicMax(&rowmax[grow], fenc(v));
      }
    }
  }
  // Col maxes: max over mi,r in-lane (16 vals), then across the 4 quad-groups.
#pragma unroll
  for (int ni = 0; ni < 4; ++ni) {
    float v = -3.402823466e38f;
#pragma unroll
    for (int mi = 0; mi < 4; ++mi)
#pragma unroll
      for (int r = 0; r < 4; ++r) v = fmaxf(v, acc[mi][ni][r]);
    v = fmaxf(v, __shfl_xor(v, 16, 64));
    v = fmaxf(v, __shfl_xor(v, 32, 64));
    if (quad == 0) {
      const int gcol = bn * TM + wn * 64 + ni * 16 + l16;
      atomicMax(&colmax[gcol], fenc(v));
    }
  }
}

__global__ __launch_bounds__(256) void finalize_kernel(
    const int* __restrict__ rowmax, const int* __restrict__ colmax,
    float* __restrict__ out) {
  const int tid = threadIdx.x;
  float s1 = 0.f, s2 = 0.f;
  for (int i = tid; i < N_ROWS; i += 256) {
    s1 += 1.0f - fdec(rowmax[i]);
    s2 += 1.0f - fdec(colmax[i]);
  }
#pragma unroll
  for (int off = 32; off > 0; off >>= 1) {
    s1 += __shfl_down(s1, off, 64);
    s2 += __shfl_down(s2, off, 64);
  }
  __shared__ float r1[4], r2[4];
  if ((tid & 63) == 0) {
    r1[tid >> 6] = s1;
    r2[tid >> 6] = s2;
  }
  __syncthreads();
  if (tid == 0) {
    const double SIGMA = 0.3;
    const double H_CONST = 0.5 * log(2.0 * 3.14159265358979323846 * SIGMA * SIGMA) + 0.5;
    const float HS = (float)(H_CONST / SIGMA);
    out[0] = HS * (r1[0] + r1[1] + r1[2] + r1[3]);
    out[1] = HS * (r2[0] + r2[1] + r2[2] + r2[3]);
  }
}

extern "C" void kernel_launch(void* const* d_in, const int* in_sizes, int n_in,
                              void* d_out, int out_size, void* d_ws, size_t ws_size,
                              hipStream_t stream) {
  const float* ex = (const float*)d_in[0];
  const float* ey = (const float*)d_in[1];
  float* out = (float*)d_out;
  char* ws = (char*)d_ws;

  unsigned short* exn = (unsigned short*)ws;                                   // 16 MB
  unsigned short* eyn = (unsigned short*)(ws + (size_t)N_ROWS * KDIM * 2);     // 16 MB
  int* rowmax = (int*)(ws + (size_t)N_ROWS * KDIM * 4);                        // 32 KB
  int* colmax = rowmax + N_ROWS;                                               // 32 KB

  normalize_kernel<<<N_ROWS, 256, 0, stream>>>(ex, exn, rowmax);
  normalize_kernel<<<N_ROWS, 256, 0, stream>>>(ey, eyn, colmax);
  gemm_max_kernel<<<dim3(64, 64), 256, 0, stream>>>(exn, eyn, rowmax, colmax);
  finalize_kernel<<<1, 256, 0, stream>>>(rowmax, colmax, out);
}

// Round 2
// 267.595 us; speedup vs baseline: 1.0487x; 1.0487x over previous
//
#include <hip/hip_runtime.h>
#include <math.h>

typedef short short8 __attribute__((ext_vector_type(8)));
typedef float floatx4 __attribute__((ext_vector_type(4)));

#define N_ROWS 8192
#define KDIM 1024

// fp32 -> bf16 round-to-nearest-even
__device__ __forceinline__ unsigned short f2bf(float f) {
  unsigned int u = __float_as_uint(f);
  u += 0x7fffu + ((u >> 16) & 1u);
  return (unsigned short)(u >> 16);
}

// order-preserving float->int encoding for atomicMax
__device__ __forceinline__ int fenc(float f) {
  int i = __float_as_int(f);
  return i >= 0 ? i : (i ^ 0x7fffffff);
}
__device__ __forceinline__ float fdec(int e) {
  int b = e >= 0 ? e : (e ^ 0x7fffffff);
  return __int_as_float(b);
}

// Fused: one block per row of ex (b < 8192) or ey (b >= 8192).
// Computes 1/||x||, writes normalized bf16 row, inits the max slot.
__global__ __launch_bounds__(256) void normalize_kernel(
    const float* __restrict__ ex, const float* __restrict__ ey,
    unsigned short* __restrict__ exn, unsigned short* __restrict__ eyn,
    int* __restrict__ rowmax, int* __restrict__ colmax) {
  const int b = blockIdx.x;
  const int tid = threadIdx.x;
  const float* x;
  unsigned short* out;
  int* mslot;
  int row;
  if (b < N_ROWS) {
    x = ex; out = exn; mslot = rowmax; row = b;
  } else {
    x = ey; out = eyn; mslot = colmax; row = b - N_ROWS;
  }
  const float4* xr = (const float4*)(x + (size_t)row * KDIM);
  float4 v = xr[tid];  // 256 threads * 4 = 1024 elements
  float ss = v.x * v.x + v.y * v.y + v.z * v.z + v.w * v.w;
#pragma unroll
  for (int off = 32; off > 0; off >>= 1) ss += __shfl_down(ss, off, 64);
  __shared__ float sred[4];
  if ((tid & 63) == 0) sred[tid >> 6] = ss;
  __syncthreads();
  const float total = sred[0] + sred[1] + sred[2] + sred[3];
  const float rnorm = rsqrtf(fmaxf(total, 1e-24f));
  ushort4 o;
  o.x = f2bf(v.x * rnorm);
  o.y = f2bf(v.y * rnorm);
  o.z = f2bf(v.z * rnorm);
  o.w = f2bf(v.w * rnorm);
  ((ushort4*)(out + (size_t)row * KDIM))[tid] = o;
  if (tid == 0) mslot[row] = (int)0x80000000;  // encoded -inf floor
}

// 128x128 tile GEMM (A @ B^T, both row-major K-contiguous bf16) fused with
// row-max / col-max reduction into global encoded-int atomics.
//
// LDS layout is XOR-swizzled to kill ds_read_b128 bank conflicts:
// 16B chunk c of tile row r lives at slot s = c ^ ((r>>1)&3). Staging picks
// the matching global source chunk per lane (dest of global_load_lds is
// fixed at wave-base + lane*16); fragment reads apply the same XOR.
// Result: 2-way bank aliasing only (free per m136) instead of 8-way.
__global__ __launch_bounds__(256) void gemm_max_kernel(
    const unsigned short* __restrict__ A, const unsigned short* __restrict__ B,
    int* __restrict__ rowmax, int* __restrict__ colmax) {
  constexpr int TM = 128, BK = 32, K = KDIM;
  __shared__ unsigned short sA[TM * BK];  // 8 KB, swizzled 128 x 32
  __shared__ unsigned short sB[TM * BK];  // 8 KB

  const int bm = blockIdx.x, bn = blockIdx.y;
  const int tid = threadIdx.x;
  const int lane = tid & 63, wave = tid >> 6;
  const int wm = wave >> 1, wn = wave & 1;  // 2x2 waves of 64x64
  const int quad = lane >> 4, l16 = lane & 15;

  const char* Ab = (const char*)(A + (size_t)bm * TM * K);
  const char* Bb = (const char*)(B + (size_t)bn * TM * K);

  floatx4 acc[4][4] = {};

  const int o_l0 = wave * 2048;  // this wave's byte window within the 8KB tile
  // staging-side source chunk for this lane (see swizzle comment above):
  // dest chunk s = lane&3, dest row r has f(r) = (lane>>3)&3.
  const int src_c = (lane & 3) ^ ((lane >> 3) & 3);
  // fragment-read-side swizzled chunk (frag rows are base16 + l16):
  const int sw = quad ^ ((l16 >> 1) & 3);

  for (int k0 = 0; k0 < K; k0 += BK) {
#pragma unroll
    for (int j = 0; j < 2; ++j) {
      const int obase = o_l0 + j * 1024;       // wave-uniform LDS byte base
      const int o = obase + lane * 16;         // this lane's dest byte offset
      const int r = o >> 6;                    // dest tile row (64 B per row)
      const char* ga = Ab + (size_t)r * (K * 2) + (size_t)k0 * 2 + src_c * 16;
      const char* gb = Bb + (size_t)r * (K * 2) + (size_t)k0 * 2 + src_c * 16;
      __builtin_amdgcn_global_load_lds(
          (__attribute__((address_space(1))) void*)ga,
          (__attribute__((address_space(3))) void*)(((char*)sA) + obase), 16, 0, 0);
      __builtin_amdgcn_global_load_lds(
          (__attribute__((address_space(1))) void*)gb,
          (__attribute__((address_space(3))) void*)(((char*)sB) + obase), 16, 0, 0);
    }
    __syncthreads();

    short8 aF[4], bF[4];
#pragma unroll
    for (int mi = 0; mi < 4; ++mi)
      aF[mi] = *(const short8*)&sA[(wm * 64 + mi * 16 + l16) * BK + sw * 8];
#pragma unroll
    for (int ni = 0; ni < 4; ++ni)
      bF[ni] = *(const short8*)&sB[(wn * 64 + ni * 16 + l16) * BK + sw * 8];

#pragma unroll
    for (int mi = 0; mi < 4; ++mi)
#pragma unroll
      for (int ni = 0; ni < 4; ++ni)
        acc[mi][ni] = __builtin_amdgcn_mfma_f32_16x16x32_bf16(
            aF[mi], bF[ni], acc[mi][ni], 0, 0, 0);
    __syncthreads();
  }

  // C/D layout (verified m89): col = lane&15, row = quad*4 + reg.
  // Row maxes: max over 4 ni in-lane, then across the 16 lanes of a quad-group.
#pragma unroll
  for (int mi = 0; mi < 4; ++mi) {
#pragma unroll
    for (int r = 0; r < 4; ++r) {
      float v = fmaxf(fmaxf(acc[mi][0][r], acc[mi][1][r]),
                      fmaxf(acc[mi][2][r], acc[mi][3][r]));
#pragma unroll
      for (int m = 1; m < 16; m <<= 1) v = fmaxf(v, __shfl_xor(v, m, 64));
      if (l16 == 0) {
        const int grow = bm * TM + wm * 64 + mi * 16 + quad * 4 + r;
        atomicMax(&rowmax[grow], fenc(v));
      }
    }
  }
  // Col maxes: max over mi,r in-lane (16 vals), then across the 4 quad-groups.
#pragma unroll
  for (int ni = 0; ni < 4; ++ni) {
    float v = -3.402823466e38f;
#pragma unroll
    for (int mi = 0; mi < 4; ++mi)
#pragma unroll
      for (int r = 0; r < 4; ++r) v = fmaxf(v, acc[mi][ni][r]);
    v = fmaxf(v, __shfl_xor(v, 16, 64));
    v = fmaxf(v, __shfl_xor(v, 32, 64));
    if (quad == 0) {
      const int gcol = bn * TM + wn * 64 + ni * 16 + l16;
      atomicMax(&colmax[gcol], fenc(v));
    }
  }
}

__global__ __launch_bounds__(1024) void finalize_kernel(
    const int* __restrict__ rowmax, const int* __restrict__ colmax,
    float* __restrict__ out) {
  const int tid = threadIdx.x;
  float s1 = 0.f, s2 = 0.f;
  for (int i = tid; i < N_ROWS; i += 1024) {
    s1 += 1.0f - fdec(rowmax[i]);
    s2 += 1.0f - fdec(colmax[i]);
  }
#pragma unroll
  for (int off = 32; off > 0; off >>= 1) {
    s1 += __shfl_down(s1, off, 64);
    s2 += __shfl_down(s2, off, 64);
  }
  __shared__ float r1[16], r2[16];
  if ((tid & 63) == 0) {
    r1[tid >> 6] = s1;
    r2[tid >> 6] = s2;
  }
  __syncthreads();
  if (tid == 0) {
    const double SIGMA = 0.3;
    const double H_CONST = 0.5 * log(2.0 * 3.14159265358979323846 * SIGMA * SIGMA) + 0.5;
    const float HS = (float)(H_CONST / SIGMA);
    float a1 = 0.f, a2 = 0.f;
#pragma unroll
    for (int w = 0; w < 16; ++w) {
      a1 += r1[w];
      a2 += r2[w];
    }
    out[0] = HS * a1;
    out[1] = HS * a2;
  }
}

extern "C" void kernel_launch(void* const* d_in, const int* in_sizes, int n_in,
                              void* d_out, int out_size, void* d_ws, size_t ws_size,
                              hipStream_t stream) {
  const float* ex = (const float*)d_in[0];
  const float* ey = (const float*)d_in[1];
  float* out = (float*)d_out;
  char* ws = (char*)d_ws;

  unsigned short* exn = (unsigned short*)ws;                                   // 16 MB
  unsigned short* eyn = (unsigned short*)(ws + (size_t)N_ROWS * KDIM * 2);     // 16 MB
  int* rowmax = (int*)(ws + (size_t)N_ROWS * KDIM * 4);                        // 32 KB
  int* colmax = rowmax + N_ROWS;                                               // 32 KB

  normalize_kernel<<<2 * N_ROWS, 256, 0, stream>>>(ex, ey, exn, eyn, rowmax, colmax);
  gemm_max_kernel<<<dim3(64, 64), 256, 0, stream>>>(exn, eyn, rowmax, colmax);
  finalize_kernel<<<1, 1024, 0, stream>>>(rowmax, colmax, out);
}